// Round 7
// baseline (469.414 us; speedup 1.0000x reference)
//
#include <hip/hip_runtime.h>
#include <hip/hip_bf16.h>
#include <stdint.h>

#define HID 256
#define BATCH 64
#define SEQ 4096

typedef __attribute__((ext_vector_type(8))) short bf16x8;
typedef __attribute__((ext_vector_type(4))) short short4v;
typedef __attribute__((ext_vector_type(4))) float f32x4;

static __device__ __forceinline__ unsigned short f2bf(float f) {
    union { float f; uint32_t u; } v; v.f = f;
    uint32_t u = v.u;
    return (unsigned short)((u + 0x7FFF + ((u >> 16) & 1)) >> 16);  // RNE
}

static __device__ __forceinline__ float bf2f(unsigned short b) {
    union { uint32_t u; float f; } v; v.u = ((uint32_t)b) << 16;
    return v.f;
}

static __device__ __forceinline__ float fast_tanh(float x) {
    float cx = fminf(fmaxf(x, -15.f), 15.f);
    float e = __expf(2.f * cx);
    return (e - 1.f) / (e + 1.f);
}

// ---------------- prep (merged): blocks 0..255 -> WFt col; 256..319 -> ut row ------
__global__ __launch_bounds__(256) void prep_kernel(const float* __restrict__ WF,
                                                   const float* __restrict__ Wt,
                                                   const float* __restrict__ o,
                                                   unsigned short* __restrict__ WFt,
                                                   float* __restrict__ ut) {
    __shared__ float ol[HID];
    int bid = blockIdx.x, t = threadIdx.x;
    if (bid < 256) {
        WFt[bid * HID + t] = f2bf(WF[t * HID + bid]);
    } else {
        int b = bid - 256;
        ol[t] = o[(size_t)(b * SEQ + SEQ - 1) * HID + t];
        __syncthreads();
        const float* wrow = Wt + t * HID;
        float acc = 0.f;
        #pragma unroll 16
        for (int k = 0; k < HID; k += 4) {
            float4 w4 = *(const float4*)(wrow + k);
            float4 o4 = *(const float4*)(ol + k);
            acc += w4.x * o4.x + w4.y * o4.y + w4.z * o4.z + w4.w * o4.w;
        }
        ut[b * HID + t] = acc;
    }
}

// ---------------- fused: stage tile once -> st + sf + local softmax + partials -----
// grid 4096 = 64 b x 64 chunks of 64 rows. 4 waves; wave w owns cols w*64..+63 (MFMA).
// LDS 36.3 KB -> 4 blocks/CU. Staging in 2 halves of 8 float4 (peak live regs:
// phase1 ~50, phase2 ~106 < 128) so __launch_bounds__(256,4) does NOT spill.
__global__ __launch_bounds__(256, 4) void fused_kernel(const float* __restrict__ o,
                                                       const unsigned short* __restrict__ WFt,
                                                       const float* __restrict__ ut,
                                                       const float* __restrict__ vF,
                                                       float* __restrict__ pT,
                                                       float* __restrict__ pF,
                                                       float* __restrict__ stats4) {
    __shared__ __align__(16) unsigned short o_sm[64 * HID];  // 32 KB, XOR-swizzled
    __shared__ float u_sm[HID];     // 1 KB
    __shared__ float red_sm[256];   // st partials [row][lg], 1 KB
    __shared__ float sfr[256];      // sf partials [w][64], 1 KB
    __shared__ float st_sm[64], sf_sm[64], wT_sm[64], wF_sm[64];  // 1 KB

    int t = threadIdx.x;
    int lane = t & 63, w = t >> 6;
    int bid = blockIdx.x;
    int b = bid >> 6;
    int s0 = (bid & 63) << 6;
    int lm = lane & 15, lg = lane >> 4;

    u_sm[t] = ut[b * HID + t];
    __syncthreads();

    const float* pbase = o + (size_t)(b * SEQ + s0) * HID + t * 4;
    const float4 u4 = *(const float4*)&u_sm[lane << 2];

    // ---- phase 1: stage 64x256 tile in 2 halves of 8 in-flight float4 loads ----
    #pragma unroll
    for (int half = 0; half < 2; half++) {
        float4 v[8];
        #pragma unroll
        for (int k = 0; k < 8; k++)
            v[k] = *(const float4*)(pbase + (half * 8 + k) * 1024);
        #pragma unroll
        for (int k = 0; k < 8; k++) {
            int j = half * 8 + k;
            int row = j * 4 + w;
            float p = v[k].x * u4.x + v[k].y * u4.y + v[k].z * u4.z + v[k].w * u4.w;
            p += __shfl_xor(p, 1);
            p += __shfl_xor(p, 2);
            p += __shfl_xor(p, 4);
            p += __shfl_xor(p, 8);
            if (lm == 0) red_sm[(row << 2) + lg] = p;
            int byte = (row << 9) + (lane << 3);
            byte ^= (row & 7) << 4;
            short4v sv;
            sv.x = (short)f2bf(v[k].x); sv.y = (short)f2bf(v[k].y);
            sv.z = (short)f2bf(v[k].z); sv.w = (short)f2bf(v[k].w);
            *(short4v*)((char*)o_sm + byte) = sv;
        }
    }
    __syncthreads();

    if (t < 64) {
        const float* r4 = &red_sm[t << 2];
        st_sm[t] = r4[0] + r4[1] + r4[2] + r4[3];
    }

    // ---- phase 2: MFMA 64x256, K=256 ----
    f32x4 acc[4][4];
    #pragma unroll
    for (int ar = 0; ar < 4; ar++)
        #pragma unroll
        for (int cb = 0; cb < 4; cb++)
            acc[ar][cb] = (f32x4){0.f, 0.f, 0.f, 0.f};

    int cw = w << 6;
    #pragma unroll
    for (int kk = 0; kk < 8; kk++) {
        int h0 = kk * 32 + lg * 8;
        bf16x8 bf[4], af[4];
        #pragma unroll
        for (int cb = 0; cb < 4; cb++) {
            int c = cw + cb * 16 + lm;
            bf[cb] = *(const bf16x8*)(WFt + (size_t)c * HID + h0);
        }
        #pragma unroll
        for (int ar = 0; ar < 4; ar++) {
            int row = ar * 16 + lm;
            int byte = (row << 9) + h0 * 2;
            byte ^= (row & 7) << 4;
            af[ar] = *(const bf16x8*)((const char*)o_sm + byte);
        }
        #pragma unroll
        for (int ar = 0; ar < 4; ar++)
            #pragma unroll
            for (int cb = 0; cb < 4; cb++)
                acc[ar][cb] = __builtin_amdgcn_mfma_f32_16x16x32_bf16(af[ar], bf[cb], acc[ar][cb], 0, 0, 0);
    }

    // ---- phase 3: tanh epilogue -> sf row sums ----
    float vf[4];
    #pragma unroll
    for (int cb = 0; cb < 4; cb++) vf[cb] = vF[cw + cb * 16 + lm];

    #pragma unroll
    for (int ar = 0; ar < 4; ar++) {
        #pragma unroll
        for (int i = 0; i < 4; i++) {
            float p = 0.f;
            #pragma unroll
            for (int cb = 0; cb < 4; cb++)
                p += fast_tanh(acc[ar][cb][i]) * vf[cb];
            p += __shfl_xor(p, 1);
            p += __shfl_xor(p, 2);
            p += __shfl_xor(p, 4);
            p += __shfl_xor(p, 8);
            if (lm == 0) sfr[w * 64 + ar * 16 + lg * 4 + i] = p;
        }
    }
    __syncthreads();
    if (t < 64) sf_sm[t] = sfr[t] + sfr[64 + t] + sfr[128 + t] + sfr[192 + t];
    __syncthreads();

    // ---- phase 4: local softmax stats (wave 0), un-normalized weights ----
    if (t < 64) {
        float vT = st_sm[t], vfv = sf_sm[t];
        float mT = vT, mF = vfv;
        #pragma unroll
        for (int d = 1; d < 64; d <<= 1) {
            mT = fmaxf(mT, __shfl_xor(mT, d));
            mF = fmaxf(mF, __shfl_xor(mF, d));
        }
        float wT = __expf(vT - mT), wF = __expf(vfv - mF);
        wT_sm[t] = wT; wF_sm[t] = wF;
        float lT = wT, lF = wF;
        #pragma unroll
        for (int d = 1; d < 64; d <<= 1) {
            lT += __shfl_xor(lT, d);
            lF += __shfl_xor(lF, d);
        }
        if (t == 0) {
            float* s4 = stats4 + (size_t)bid * 4;
            s4[0] = mT; s4[1] = lT; s4[2] = mF; s4[3] = lF;
        }
    }
    __syncthreads();

    // ---- phase 5: weighted partial sums from LDS tile (bf16) ----
    float4 aT = {0.f, 0.f, 0.f, 0.f}, aF = {0.f, 0.f, 0.f, 0.f};
    #pragma unroll
    for (int j = 0; j < 16; j++) {
        int row = j * 4 + w;
        int byte = (row << 9) + (lane << 3);
        byte ^= (row & 7) << 4;
        short4v sv = *(const short4v*)((const char*)o_sm + byte);
        float x0 = bf2f((unsigned short)sv.x), x1 = bf2f((unsigned short)sv.y);
        float x2 = bf2f((unsigned short)sv.z), x3 = bf2f((unsigned short)sv.w);
        float wt = wT_sm[row], wf = wF_sm[row];
        aT.x += wt * x0; aT.y += wt * x1; aT.z += wt * x2; aT.w += wt * x3;
        aF.x += wf * x0; aF.y += wf * x1; aF.z += wf * x2; aF.w += wf * x3;
    }
    __syncthreads();  // all o_sm reads done; alias its space for the reduction
    float4* pTa = (float4*)&o_sm[0];     // 4 KB
    float4* pFa = (float4*)&o_sm[2048];  // 4 KB
    pTa[w * 64 + lane] = aT;
    pFa[w * 64 + lane] = aF;
    __syncthreads();

    if (t < 64) {
        float4 s = pTa[t];
        #pragma unroll
        for (int ww = 1; ww < 4; ww++) {
            float4 q = pTa[ww * 64 + t];
            s.x += q.x; s.y += q.y; s.z += q.z; s.w += q.w;
        }
        *(float4*)(pT + (size_t)bid * HID + (t << 2)) = s;
    } else if (t < 128) {
        int tt = t - 64;
        float4 s = pFa[tt];
        #pragma unroll
        for (int ww = 1; ww < 4; ww++) {
            float4 q = pFa[ww * 64 + tt];
            s.x += q.x; s.y += q.y; s.z += q.z; s.w += q.w;
        }
        *(float4*)(pF + (size_t)bid * HID + (tt << 2)) = s;
    }
}

// ---------------- combine: rescale chunk partials -> final output ----------------
// grid (64, 2): y=0 -> T, y=1 -> F.
__global__ __launch_bounds__(256) void combine_kernel(const float* __restrict__ pT,
                                                      const float* __restrict__ pF,
                                                      const float* __restrict__ stats4,
                                                      float* __restrict__ out) {
    __shared__ float eW[64];
    __shared__ float scale;
    int b = blockIdx.x, which = blockIdx.y, t = threadIdx.x;
    const float* P = which ? pF : pT;
    if (t < 64) {
        const float* s4 = stats4 + (size_t)(b * 64 + t) * 4;
        float m = s4[which * 2], l = s4[which * 2 + 1];
        float M = m;
        #pragma unroll
        for (int d = 1; d < 64; d <<= 1) M = fmaxf(M, __shfl_xor(M, d));
        float e = __expf(m - M);
        eW[t] = e;
        float L = e * l;
        #pragma unroll
        for (int d = 1; d < 64; d <<= 1) L += __shfl_xor(L, d);
        if (t == 0) scale = L;
    }
    __syncthreads();
    float acc = 0.f;
    const float* Pb = P + (size_t)b * 64 * HID + t;
    #pragma unroll 8
    for (int c = 0; c < 64; c++) acc += eW[c] * Pb[(size_t)c * HID];
    out[b * 512 + which * 256 + t] = acc / scale;
}

extern "C" void kernel_launch(void* const* d_in, const int* in_sizes, int n_in,
                              void* d_out, int out_size, void* d_ws, size_t ws_size,
                              hipStream_t stream) {
    const float* o  = (const float*)d_in[0];
    const float* Wt = (const float*)d_in[1];
    const float* WF = (const float*)d_in[2];
    const float* vF = (const float*)d_in[3];
    float* out = (float*)d_out;
    char* ws = (char*)d_ws;

    unsigned short* WFt = (unsigned short*)ws;                    // 128 KB
    float* ut     = (float*)(ws + 131072);                        // 64 KB
    float* pT     = (float*)(ws + 196608);                        // 4 MB
    float* pF     = (float*)(ws + 196608 + 4194304);              // 4 MB
    float* stats4 = (float*)(ws + 196608 + 8388608);              // 64 KB

    prep_kernel<<<320, 256, 0, stream>>>(WF, Wt, o, WFt, ut);
    fused_kernel<<<BATCH * 64, 256, 0, stream>>>(o, WFt, ut, vF, pT, pF, stats4);
    combine_kernel<<<dim3(64, 2), 256, 0, stream>>>(pT, pF, stats4, out);
}

// Round 10
// 456.816 us; speedup vs baseline: 1.0276x; 1.0276x over previous
//
#include <hip/hip_runtime.h>
#include <hip/hip_bf16.h>
#include <stdint.h>

#define HID 256
#define BATCH 64
#define SEQ 4096

typedef __attribute__((ext_vector_type(8))) short bf16x8;
typedef __attribute__((ext_vector_type(4))) short short4v;
typedef __attribute__((ext_vector_type(4))) float f32x4;

static __device__ __forceinline__ unsigned short f2bf(float f) {
    union { float f; uint32_t u; } v; v.f = f;
    uint32_t u = v.u;
    return (unsigned short)((u + 0x7FFF + ((u >> 16) & 1)) >> 16);  // RNE
}

static __device__ __forceinline__ float bf2f(unsigned short b) {
    union { uint32_t u; float f; } v; v.u = ((uint32_t)b) << 16;
    return v.f;
}

static __device__ __forceinline__ float fast_tanh(float x) {
    float cx = fminf(fmaxf(x, -15.f), 15.f);
    float e = __expf(2.f * cx);
    return (e - 1.f) / (e + 1.f);
}

// ---------------- prep (merged): blocks 0..255 -> WFt col; 256..319 -> ut row ------
__global__ __launch_bounds__(256) void prep_kernel(const float* __restrict__ WF,
                                                   const float* __restrict__ Wt,
                                                   const float* __restrict__ o,
                                                   unsigned short* __restrict__ WFt,
                                                   float* __restrict__ ut) {
    __shared__ float ol[HID];
    int bid = blockIdx.x, t = threadIdx.x;
    if (bid < 256) {
        WFt[bid * HID + t] = f2bf(WF[t * HID + bid]);
    } else {
        int b = bid - 256;
        ol[t] = o[(size_t)(b * SEQ + SEQ - 1) * HID + t];
        __syncthreads();
        const float* wrow = Wt + t * HID;
        float acc = 0.f;
        #pragma unroll 16
        for (int k = 0; k < HID; k += 4) {
            float4 w4 = *(const float4*)(wrow + k);
            float4 o4 = *(const float4*)(ol + k);
            acc += w4.x * o4.x + w4.y * o4.y + w4.z * o4.z + w4.w * o4.w;
        }
        ut[b * HID + t] = acc;
    }
}

// ---------------- fused: stage tile once -> st + sf + local softmax + partials -----
// grid 4096 = 64 b x 64 chunks of 64 rows. 4 waves; wave w owns cols w*64..+63 (MFMA).
// LDS 36.3 KB -> 4 blocks/CU (LDS-limited). NO min-wave clamp: acc[4][4]=64 AGPR +
// fragments/staging need ~150 unified regs; clamping to 128 (=4 waves/SIMD) caused
// 280 MB of scratch spill traffic (R5/R7: VGPR=64, WRITE_SIZE=145MB). 3 waves/SIMD
// from regs is fine: 3 blocks x 64 in-flight float4/CU covers HBM latency.
__global__ __launch_bounds__(256) void fused_kernel(const float* __restrict__ o,
                                                    const unsigned short* __restrict__ WFt,
                                                    const float* __restrict__ ut,
                                                    const float* __restrict__ vF,
                                                    float* __restrict__ pT,
                                                    float* __restrict__ pF,
                                                    float* __restrict__ stats4) {
    __shared__ __align__(16) unsigned short o_sm[64 * HID];  // 32 KB, XOR-swizzled
    __shared__ float u_sm[HID];     // 1 KB
    __shared__ float red_sm[256];   // st partials [row][lg], 1 KB
    __shared__ float sfr[256];      // sf partials [w][64], 1 KB
    __shared__ float st_sm[64], sf_sm[64], wT_sm[64], wF_sm[64];  // 1 KB

    int t = threadIdx.x;
    int lane = t & 63, w = t >> 6;
    int bid = blockIdx.x;
    int b = bid >> 6;
    int s0 = (bid & 63) << 6;
    int lm = lane & 15, lg = lane >> 4;

    u_sm[t] = ut[b * HID + t];
    __syncthreads();

    const float* pbase = o + (size_t)(b * SEQ + s0) * HID + t * 4;
    const float4 u4 = *(const float4*)&u_sm[lane << 2];

    // ---- phase 1: stage 64x256 tile in 2 halves of 8 in-flight float4 loads ----
    #pragma unroll
    for (int half = 0; half < 2; half++) {
        float4 v[8];
        #pragma unroll
        for (int k = 0; k < 8; k++)
            v[k] = *(const float4*)(pbase + (half * 8 + k) * 1024);
        #pragma unroll
        for (int k = 0; k < 8; k++) {
            int j = half * 8 + k;
            int row = j * 4 + w;
            float p = v[k].x * u4.x + v[k].y * u4.y + v[k].z * u4.z + v[k].w * u4.w;
            p += __shfl_xor(p, 1);
            p += __shfl_xor(p, 2);
            p += __shfl_xor(p, 4);
            p += __shfl_xor(p, 8);
            if (lm == 0) red_sm[(row << 2) + lg] = p;
            int byte = (row << 9) + (lane << 3);
            byte ^= (row & 7) << 4;
            short4v sv;
            sv.x = (short)f2bf(v[k].x); sv.y = (short)f2bf(v[k].y);
            sv.z = (short)f2bf(v[k].z); sv.w = (short)f2bf(v[k].w);
            *(short4v*)((char*)o_sm + byte) = sv;
        }
    }
    __syncthreads();

    if (t < 64) {
        const float* r4 = &red_sm[t << 2];
        st_sm[t] = r4[0] + r4[1] + r4[2] + r4[3];
    }

    // ---- phase 2: MFMA 64x256, K=256 ----
    f32x4 acc[4][4];
    #pragma unroll
    for (int ar = 0; ar < 4; ar++)
        #pragma unroll
        for (int cb = 0; cb < 4; cb++)
            acc[ar][cb] = (f32x4){0.f, 0.f, 0.f, 0.f};

    int cw = w << 6;
    #pragma unroll
    for (int kk = 0; kk < 8; kk++) {
        int h0 = kk * 32 + lg * 8;
        bf16x8 bf[4], af[4];
        #pragma unroll
        for (int cb = 0; cb < 4; cb++) {
            int c = cw + cb * 16 + lm;
            bf[cb] = *(const bf16x8*)(WFt + (size_t)c * HID + h0);
        }
        #pragma unroll
        for (int ar = 0; ar < 4; ar++) {
            int row = ar * 16 + lm;
            int byte = (row << 9) + h0 * 2;
            byte ^= (row & 7) << 4;
            af[ar] = *(const bf16x8*)((const char*)o_sm + byte);
        }
        #pragma unroll
        for (int ar = 0; ar < 4; ar++)
            #pragma unroll
            for (int cb = 0; cb < 4; cb++)
                acc[ar][cb] = __builtin_amdgcn_mfma_f32_16x16x32_bf16(af[ar], bf[cb], acc[ar][cb], 0, 0, 0);
    }

    // ---- phase 3: tanh epilogue -> sf row sums ----
    float vf[4];
    #pragma unroll
    for (int cb = 0; cb < 4; cb++) vf[cb] = vF[cw + cb * 16 + lm];

    #pragma unroll
    for (int ar = 0; ar < 4; ar++) {
        #pragma unroll
        for (int i = 0; i < 4; i++) {
            float p = 0.f;
            #pragma unroll
            for (int cb = 0; cb < 4; cb++)
                p += fast_tanh(acc[ar][cb][i]) * vf[cb];
            p += __shfl_xor(p, 1);
            p += __shfl_xor(p, 2);
            p += __shfl_xor(p, 4);
            p += __shfl_xor(p, 8);
            if (lm == 0) sfr[w * 64 + ar * 16 + lg * 4 + i] = p;
        }
    }
    __syncthreads();
    if (t < 64) sf_sm[t] = sfr[t] + sfr[64 + t] + sfr[128 + t] + sfr[192 + t];
    __syncthreads();

    // ---- phase 4: local softmax stats (wave 0), un-normalized weights ----
    if (t < 64) {
        float vT = st_sm[t], vfv = sf_sm[t];
        float mT = vT, mF = vfv;
        #pragma unroll
        for (int d = 1; d < 64; d <<= 1) {
            mT = fmaxf(mT, __shfl_xor(mT, d));
            mF = fmaxf(mF, __shfl_xor(mF, d));
        }
        float wT = __expf(vT - mT), wF = __expf(vfv - mF);
        wT_sm[t] = wT; wF_sm[t] = wF;
        float lT = wT, lF = wF;
        #pragma unroll
        for (int d = 1; d < 64; d <<= 1) {
            lT += __shfl_xor(lT, d);
            lF += __shfl_xor(lF, d);
        }
        if (t == 0) {
            float* s4 = stats4 + (size_t)bid * 4;
            s4[0] = mT; s4[1] = lT; s4[2] = mF; s4[3] = lF;
        }
    }
    __syncthreads();

    // ---- phase 5: weighted partial sums from LDS tile (bf16) ----
    float4 aT = {0.f, 0.f, 0.f, 0.f}, aF = {0.f, 0.f, 0.f, 0.f};
    #pragma unroll
    for (int j = 0; j < 16; j++) {
        int row = j * 4 + w;
        int byte = (row << 9) + (lane << 3);
        byte ^= (row & 7) << 4;
        short4v sv = *(const short4v*)((const char*)o_sm + byte);
        float x0 = bf2f((unsigned short)sv.x), x1 = bf2f((unsigned short)sv.y);
        float x2 = bf2f((unsigned short)sv.z), x3 = bf2f((unsigned short)sv.w);
        float wt = wT_sm[row], wf = wF_sm[row];
        aT.x += wt * x0; aT.y += wt * x1; aT.z += wt * x2; aT.w += wt * x3;
        aF.x += wf * x0; aF.y += wf * x1; aF.z += wf * x2; aF.w += wf * x3;
    }
    __syncthreads();  // all o_sm reads done; alias its space for the reduction
    float4* pTa = (float4*)&o_sm[0];     // 4 KB
    float4* pFa = (float4*)&o_sm[2048];  // 4 KB
    pTa[w * 64 + lane] = aT;
    pFa[w * 64 + lane] = aF;
    __syncthreads();

    if (t < 64) {
        float4 s = pTa[t];
        #pragma unroll
        for (int ww = 1; ww < 4; ww++) {
            float4 q = pTa[ww * 64 + t];
            s.x += q.x; s.y += q.y; s.z += q.z; s.w += q.w;
        }
        *(float4*)(pT + (size_t)bid * HID + (t << 2)) = s;
    } else if (t < 128) {
        int tt = t - 64;
        float4 s = pFa[tt];
        #pragma unroll
        for (int ww = 1; ww < 4; ww++) {
            float4 q = pFa[ww * 64 + tt];
            s.x += q.x; s.y += q.y; s.z += q.z; s.w += q.w;
        }
        *(float4*)(pF + (size_t)bid * HID + (tt << 2)) = s;
    }
}

// ---------------- combine: rescale chunk partials -> final output ----------------
// grid (64, 2): y=0 -> T, y=1 -> F.
__global__ __launch_bounds__(256) void combine_kernel(const float* __restrict__ pT,
                                                      const float* __restrict__ pF,
                                                      const float* __restrict__ stats4,
                                                      float* __restrict__ out) {
    __shared__ float eW[64];
    __shared__ float scale;
    int b = blockIdx.x, which = blockIdx.y, t = threadIdx.x;
    const float* P = which ? pF : pT;
    if (t < 64) {
        const float* s4 = stats4 + (size_t)(b * 64 + t) * 4;
        float m = s4[which * 2], l = s4[which * 2 + 1];
        float M = m;
        #pragma unroll
        for (int d = 1; d < 64; d <<= 1) M = fmaxf(M, __shfl_xor(M, d));
        float e = __expf(m - M);
        eW[t] = e;
        float L = e * l;
        #pragma unroll
        for (int d = 1; d < 64; d <<= 1) L += __shfl_xor(L, d);
        if (t == 0) scale = L;
    }
    __syncthreads();
    float acc = 0.f;
    const float* Pb = P + (size_t)b * 64 * HID + t;
    #pragma unroll 8
    for (int c = 0; c < 64; c++) acc += eW[c] * Pb[(size_t)c * HID];
    out[b * 512 + which * 256 + t] = acc / scale;
}

extern "C" void kernel_launch(void* const* d_in, const int* in_sizes, int n_in,
                              void* d_out, int out_size, void* d_ws, size_t ws_size,
                              hipStream_t stream) {
    const float* o  = (const float*)d_in[0];
    const float* Wt = (const float*)d_in[1];
    const float* WF = (const float*)d_in[2];
    const float* vF = (const float*)d_in[3];
    float* out = (float*)d_out;
    char* ws = (char*)d_ws;

    unsigned short* WFt = (unsigned short*)ws;                    // 128 KB
    float* ut     = (float*)(ws + 131072);                        // 64 KB
    float* pT     = (float*)(ws + 196608);                        // 4 MB
    float* pF     = (float*)(ws + 196608 + 4194304);              // 4 MB
    float* stats4 = (float*)(ws + 196608 + 8388608);              // 64 KB

    prep_kernel<<<320, 256, 0, stream>>>(WF, Wt, o, WFt, ut);
    fused_kernel<<<BATCH * 64, 256, 0, stream>>>(o, WFt, ut, vF, pT, pF, stats4);
    combine_kernel<<<dim3(64, 2), 256, 0, stream>>>(pT, pF, stats4, out);
}